// Round 7
// baseline (239.102 us; speedup 1.0000x reference)
//
#include <hip/hip_runtime.h>
#include <hip/hip_bf16.h>

#define B_SZ 32
#define N_SZ 2048
#define H_SZ 1024

typedef float f32x4 __attribute__((ext_vector_type(4)));
typedef short bf16x8 __attribute__((ext_vector_type(8)));

static __device__ __forceinline__ unsigned short f2bf(float f) {
    union { float f; unsigned u; } x; x.f = f;
    unsigned r = x.u + 0x7FFF + ((x.u >> 16) & 1);
    return (unsigned short)(r >> 16);
}

// fast tanh: (e^{2x}-1)/(e^{2x}+1), clamped so e never overflows
static __device__ __forceinline__ float fast_tanh(float x) {
    x = fminf(fmaxf(x, -15.f), 15.f);
    float e = __expf(2.f * x);
    return (e - 1.f) / (e + 1.f);
}

// ---------------- kernel 1: pack Wv f32 -> bf16 in wave-fragment order ----------------
// packed element index: ((((w*32 + k)*4 + t)*64) + lane)*8 + j
//   maps to Wv[g][h], g = w*64 + 16t + (lane&15), h = k*32 + (lane>>4)*8 + j
__global__ __launch_bounds__(256) void pack_wv_kernel(const float* __restrict__ wv,
                                                      short* __restrict__ out) {
    int o8 = blockIdx.x * 256 + threadIdx.x;      // 131072 threads, 8 elems each
    int lane = o8 & 63;
    int t    = (o8 >> 6) & 3;
    int k    = (o8 >> 8) & 31;
    int w    = (o8 >> 13) & 15;
    int g  = w * 64 + 16 * t + (lane & 15);
    int h0 = k * 32 + (lane >> 4) * 8;
    const float* src = wv + (size_t)g * 1024 + h0;
    float4 v0 = *(const float4*)(src);
    float4 v1 = *(const float4*)(src + 4);
    short4 s0, s1;
    s0.x = (short)f2bf(v0.x); s0.y = (short)f2bf(v0.y);
    s0.z = (short)f2bf(v0.z); s0.w = (short)f2bf(v0.w);
    s1.x = (short)f2bf(v1.x); s1.y = (short)f2bf(v1.y);
    s1.z = (short)f2bf(v1.z); s1.w = (short)f2bf(v1.w);
    *(short4*)(out + (size_t)o8 * 8)     = s0;
    *(short4*)(out + (size_t)o8 * 8 + 4) = s1;
}

// ---------------- kernel 2: q_hid = query @ Wq.T + bias ----------------
__global__ __launch_bounds__(256) void qhid_kernel(const float* __restrict__ query,
                                                   const float* __restrict__ Wq,
                                                   const float* __restrict__ bias,
                                                   float* __restrict__ qh) {
    int gb = blockIdx.x * 4;
    __shared__ float wsm[4][1024];
    int t = threadIdx.x;
    for (int i = t; i < 4096; i += 256)
        wsm[i >> 10][i & 1023] = Wq[(size_t)gb * 1024 + i];
    __syncthreads();
    int gi = t >> 6;
    int lane = t & 63;
    int b = lane >> 1;
    int half = lane & 1;
    const float4* q = (const float4*)(query + b * 1024 + half * 512);
    const float4* w = (const float4*)(&wsm[gi][half * 512]);
    float acc = 0.f;
#pragma unroll 8
    for (int h = 0; h < 128; ++h) {
        float4 qv = q[h]; float4 wv = w[h];
        acc += qv.x * wv.x + qv.y * wv.y + qv.z * wv.z + qv.w * wv.w;
    }
    acc += __shfl_xor(acc, 1);
    if (half == 0) qh[b * 1024 + gb + gi] = acc + bias[gb + gi];
}

// ---------------- kernel 3: fused score GEMM + tanh + Wm dot ----------------
// 1024 threads (16 waves, 4 waves/SIMD); one 64-row panel per block.
// K is chunked: KC=128, 8 chunks, double-buffered LDS (2 x 16 KB). Per chunk,
// staging loads for chunk c+1 are ISSUED before chunk c's 4 k-steps (HBM latency
// hides under MFMA), converted+written after, one barrier per chunk (T14 split).
__global__ __launch_bounds__(1024, 4) void fused_score_kernel(
    const float* __restrict__ value, const float* __restrict__ cov,
    const short* __restrict__ wv_pk, const float* __restrict__ qh,
    const float* __restrict__ Wc, const float* __restrict__ Wm,
    float* __restrict__ e_out)
{
    extern __shared__ char smem[];                 // 2 x 16384 B buffers + e_sm
    float* e_sm = (float*)(smem + 32768);

    const int p   = blockIdx.x;
    const int b   = p >> 5;
    const int n0  = (p & 31) * 64;
    const int tid = threadIdx.x;

    if (tid < 64) e_sm[tid] = 0.f;

    // staging role: thread -> (row, 8-f32 column group) within the 64x128 chunk
    const int srow = tid >> 4;                     // 0..63
    const int scol = tid & 15;                     // 0..15
    const float* gsrc = value + ((size_t)(b * N_SZ + n0) + srow) * H_SZ + scol * 8;
    const unsigned wbyte = ((unsigned)(srow * 256 + scol * 16)) ^ ((unsigned)((srow & 7) << 4));

    // ---- prologue: stage chunk 0 into buf0 ----
    {
        float4 q0 = *(const float4*)(gsrc);
        float4 q1 = *(const float4*)(gsrc + 4);
        bf16x8 w;
        w[0] = (short)f2bf(q0.x); w[1] = (short)f2bf(q0.y);
        w[2] = (short)f2bf(q0.z); w[3] = (short)f2bf(q0.w);
        w[4] = (short)f2bf(q1.x); w[5] = (short)f2bf(q1.y);
        w[6] = (short)f2bf(q1.z); w[7] = (short)f2bf(q1.w);
        *(bf16x8*)(smem + wbyte) = w;
    }
    __syncthreads();

    const int wave = tid >> 6;
    const int lane = tid & 63;
    const int lrow = lane & 15;
    const int lgrp = lane >> 4;
    const unsigned xorm = (unsigned)((lrow & 7) << 4);
    // chunk-local swizzled bases (row stride 256B); ks even/odd split keeps
    // the +offset additions carry-free w.r.t. the XORed bits 4-6.
    const unsigned base_e = ((unsigned)(lrow * 256 + lgrp * 16)) ^ xorm;       // ks even
    const unsigned base_o = ((unsigned)(lrow * 256 + 64 + lgrp * 16)) ^ xorm;  // ks odd

    const short* bbase = wv_pk + (size_t)wave * 65536 + lane * 8;
    const short* bptr  = bbase;                    // advances 8192 shorts per chunk

    f32x4 acc[4][4];
#pragma unroll
    for (int r = 0; r < 4; ++r)
#pragma unroll
        for (int t = 0; t < 4; ++t) acc[r][t] = (f32x4){0.f, 0.f, 0.f, 0.f};

    // B ping buffer (flat k ping/pong, independent of chunking)
    bf16x8 bc[4];
#pragma unroll
    for (int t = 0; t < 4; ++t)
        bc[t] = *(const bf16x8*)(bbase + t * 512);

    const float* gptr = gsrc + 128;                // chunk c+1 source

#pragma unroll 2
    for (int c = 0; c < 8; ++c) {
        // issue-early: global loads for chunk c+1 (covered by the 4 k-steps)
        float4 p0, p1;
        if (c < 7) {
            p0 = *(const float4*)(gptr);
            p1 = *(const float4*)(gptr + 4);
        }
        const unsigned bufoff = (unsigned)((c & 1) * 16384);

#pragma unroll
        for (int ks = 0; ks < 4; ++ks) {
            // prefetch next flat-k B fragments (last one reads 2KB past the
            // wave-15 slice into the qh buffer - loaded but never used)
            bf16x8 bn[4];
#pragma unroll
            for (int t = 0; t < 4; ++t)
                bn[t] = *(const bf16x8*)(bptr + (ks + 1) * 2048 + t * 512);

            bf16x8 afr[4];
            const unsigned P = ((ks & 1) ? base_o : base_e) + bufoff + (unsigned)((ks >> 1) * 128);
#pragma unroll
            for (int r = 0; r < 4; ++r)
                afr[r] = *(const bf16x8*)(smem + P + (unsigned)(r * 4096));
#pragma unroll
            for (int r = 0; r < 4; ++r)
#pragma unroll
                for (int t = 0; t < 4; ++t)
                    acc[r][t] = __builtin_amdgcn_mfma_f32_16x16x32_bf16(
                        afr[r], bc[t], acc[r][t], 0, 0, 0);
#pragma unroll
            for (int t = 0; t < 4; ++t) bc[t] = bn[t];
        }
        bptr += 8192;

        // write-late: convert staged chunk and store to the other buffer
        if (c < 7) {
            bf16x8 w;
            w[0] = (short)f2bf(p0.x); w[1] = (short)f2bf(p0.y);
            w[2] = (short)f2bf(p0.z); w[3] = (short)f2bf(p0.w);
            w[4] = (short)f2bf(p1.x); w[5] = (short)f2bf(p1.y);
            w[6] = (short)f2bf(p1.z); w[7] = (short)f2bf(p1.w);
            *(bf16x8*)(smem + wbyte + (unsigned)(((c + 1) & 1) * 16384)) = w;
            gptr += 128;
        }
        __syncthreads();
    }

    // epilogue: a = acc + qh + cov*Wc ; e_part += tanh(a)*Wm
    const int gbase = wave * 64;
    float s_part[4][4];
#pragma unroll
    for (int r = 0; r < 4; ++r)
#pragma unroll
        for (int i = 0; i < 4; ++i) s_part[r][i] = 0.f;

    float cv[4][4];
#pragma unroll
    for (int r = 0; r < 4; ++r)
#pragma unroll
        for (int i = 0; i < 4; ++i)
            cv[r][i] = cov[b * N_SZ + n0 + 16 * r + lgrp * 4 + i];

#pragma unroll
    for (int t = 0; t < 4; ++t) {
        int g = gbase + 16 * t + lrow;
        float qv = qh[b * 1024 + g];
        float wc = Wc[g];
        float wm = Wm[g];
#pragma unroll
        for (int r = 0; r < 4; ++r)
#pragma unroll
            for (int i = 0; i < 4; ++i) {
                float aval = acc[r][t][i] + qv + cv[r][i] * wc;
                s_part[r][i] += fast_tanh(aval) * wm;
            }
    }

    // reduce across the 16 lanes sharing a row, then accumulate into LDS
#pragma unroll
    for (int r = 0; r < 4; ++r)
#pragma unroll
        for (int i = 0; i < 4; ++i) {
            float s = s_part[r][i];
            s += __shfl_xor(s, 1);
            s += __shfl_xor(s, 2);
            s += __shfl_xor(s, 4);
            s += __shfl_xor(s, 8);
            if (lrow == 0) atomicAdd(&e_sm[16 * r + lgrp * 4 + i], s);
        }
    __syncthreads();
    if (tid < 64) e_out[b * N_SZ + n0 + tid] = e_sm[tid];
}

// ---------------- kernel 4: mask + softmax over n ----------------
__global__ __launch_bounds__(256) void softmax_kernel(const float* __restrict__ e,
                                                      const int* __restrict__ mask,
                                                      const float* __restrict__ bm,
                                                      float* __restrict__ attn_out) {
    int b = blockIdx.x;
    int t = threadIdx.x;
    int wave = t >> 6, lane = t & 63;
    float bmv = bm[0];
    float vals[8];
    float mx = -1e30f;
#pragma unroll
    for (int j = 0; j < 8; ++j) {
        int n = t + 256 * j;
        float ev = e[b * N_SZ + n] + bmv;
        if (mask[b * N_SZ + n] <= 0) ev = -1e9f;
        vals[j] = ev;
        mx = fmaxf(mx, ev);
    }
#pragma unroll
    for (int m = 1; m < 64; m <<= 1) mx = fmaxf(mx, __shfl_xor(mx, m));
    __shared__ float redmax[4], redsum[4];
    if (lane == 0) redmax[wave] = mx;
    __syncthreads();
    mx = fmaxf(fmaxf(redmax[0], redmax[1]), fmaxf(redmax[2], redmax[3]));
    float sum = 0.f;
#pragma unroll
    for (int j = 0; j < 8; ++j) {
        vals[j] = expf(vals[j] - mx);
        sum += vals[j];
    }
#pragma unroll
    for (int m = 1; m < 64; m <<= 1) sum += __shfl_xor(sum, m);
    if (lane == 0) redsum[wave] = sum;
    __syncthreads();
    sum = redsum[0] + redsum[1] + redsum[2] + redsum[3];
    float inv = 1.f / sum;
#pragma unroll
    for (int j = 0; j < 8; ++j)
        attn_out[b * N_SZ + t + 256 * j] = vals[j] * inv;
}

// ---------------- kernel 5: partial weighted value sum (16 chunks/batch) ----------------
__global__ __launch_bounds__(256) void wsum_partial_kernel(const float* __restrict__ attn,
                                                           const float* __restrict__ value,
                                                           float* __restrict__ partial) {
    int b = blockIdx.x >> 4;
    int c = blockIdx.x & 15;
    int t = threadIdx.x;
    float4 acc = {0.f, 0.f, 0.f, 0.f};
    const float* vbase = value + (size_t)(b * N_SZ + c * 128) * H_SZ;
    const float* abase = attn + b * N_SZ + c * 128;
    for (int n = 0; n < 128; ++n) {
        float a = abase[n];
        if (a != 0.f) {
            float4 v = *(const float4*)(vbase + (size_t)n * H_SZ + t * 4);
            acc.x += a * v.x; acc.y += a * v.y;
            acc.z += a * v.z; acc.w += a * v.w;
        }
    }
    *(float4*)(partial + (size_t)blockIdx.x * H_SZ + t * 4) = acc;
}

// ---------------- kernel 6: reduce partials -> output ----------------
__global__ __launch_bounds__(256) void wsum_reduce_kernel(const float* __restrict__ partial,
                                                          float* __restrict__ out) {
    int i = blockIdx.x * 256 + threadIdx.x;   // 32768 total
    int b = i >> 10;
    int h = i & 1023;
    float s = 0.f;
#pragma unroll
    for (int c = 0; c < 16; ++c) s += partial[(size_t)(b * 16 + c) * H_SZ + h];
    out[i] = s;
}

extern "C" void kernel_launch(void* const* d_in, const int* in_sizes, int n_in,
                              void* d_out, int out_size, void* d_ws, size_t ws_size,
                              hipStream_t stream) {
    const float* query = (const float*)d_in[0];
    const float* value = (const float*)d_in[1];
    const int*   mask  = (const int*)  d_in[2];
    const float* cov   = (const float*)d_in[3];
    const float* Wq    = (const float*)d_in[4];
    const float* Wv    = (const float*)d_in[5];
    const float* Wc    = (const float*)d_in[6];
    const float* bias  = (const float*)d_in[7];
    const float* Wm    = (const float*)d_in[8];
    const float* bm    = (const float*)d_in[9];

    float* out      = (float*)d_out;            // [32*1024] output
    float* attn_out = out + B_SZ * H_SZ;        // [32*2048] attn

    char* ws = (char*)d_ws;
    short* wv_pk   = (short*)ws;                                       // 2 MB
    float* qh      = (float*)(ws + 2 * 1024 * 1024);                   // 128 KB
    float* e_buf   = (float*)(ws + 2 * 1024 * 1024 + 128 * 1024);      // 256 KB
    float* partial = (float*)(ws + 2 * 1024 * 1024 + 384 * 1024);      // 2 MB

    pack_wv_kernel<<<512, 256, 0, stream>>>(Wv, wv_pk);
    qhid_kernel<<<256, 256, 0, stream>>>(query, Wq, bias, qh);

    size_t smem = 32768 + 256;
    fused_score_kernel<<<1024, 1024, smem, stream>>>(value, cov, wv_pk, qh, Wc, Wm, e_buf);

    softmax_kernel<<<B_SZ, 256, 0, stream>>>(e_buf, mask, bm, attn_out);
    wsum_partial_kernel<<<B_SZ * 16, 256, 0, stream>>>(attn_out, value, partial);
    wsum_reduce_kernel<<<128, 256, 0, stream>>>(partial, out);
}